// Round 2
// baseline (519.134 us; speedup 1.0000x reference)
//
#include <hip/hip_runtime.h>

#define HD 64
#define SEQLEN 512
#define NBATCH 256

// LDS layout for k1 (floats)
#define LDS_W1 0          // 8192  (w1 transposed: [j][i], j=0..127, i=0..63)
#define LDS_W2 8192       // 8192  (w2 as-is: [j][m])
#define LDS_B1 16384      // 128
#define LDS_B2 16512      // 64
#define LDS_LG 16576      // 64
#define LDS_LB 16640      // 64
#define LDS_TOT 16704     // 66816 bytes -> 2 blocks/CU

// DPP controls
#define DPP_XOR1 0xB1     // quad_perm [1,0,3,2]
#define DPP_XOR2 0x4E     // quad_perm [2,3,0,1]
#define DPP_HMIR 0x141    // row_half_mirror (i <-> 7-i within 8 lanes)

__device__ __forceinline__ float dpp_add(float x, const int ctrl) {
    int y;
    switch (ctrl) {  // ctrl must be an immediate for the builtin
        case DPP_XOR1:
            y = __builtin_amdgcn_update_dpp(0, __float_as_int(x), DPP_XOR1, 0xf, 0xf, true);
            break;
        case DPP_XOR2:
            y = __builtin_amdgcn_update_dpp(0, __float_as_int(x), DPP_XOR2, 0xf, 0xf, true);
            break;
        default:
            y = __builtin_amdgcn_update_dpp(0, __float_as_int(x), DPP_HMIR, 0xf, 0xf, true);
            break;
    }
    return x + __int_as_float(y);
}

__device__ __forceinline__ float sum8(float x) {
    x = dpp_add(x, DPP_XOR1);
    x = dpp_add(x, DPP_XOR2);
    x = dpp_add(x, DPP_HMIR);
    return x;   // all 8 lanes of the group hold the sum
}

// ---------------------------------------------------------------------------
// k1: one thread per token. embed gather -> MLP -> residual -> LayerNorm ->
// normalize. Weights staged in LDS (w1 transposed during staging).
// Outputs: Kn[token][64] = normalized key rows, S[token] = max(||k||,1e-12).
// ---------------------------------------------------------------------------
__global__ __launch_bounds__(256) void k1_token(
    const int* __restrict__ seq, const float* __restrict__ embed,
    const float* __restrict__ w1, const float* __restrict__ b1,
    const float* __restrict__ w2, const float* __restrict__ b2,
    const float* __restrict__ ln_g, const float* __restrict__ ln_b,
    float* __restrict__ Kn, float* __restrict__ S)
{
    __shared__ float smem[LDS_TOT];
    const int tid = threadIdx.x;

    // ---- stage weights ----
#pragma unroll
    for (int t0 = 0; t0 < 8192; t0 += 256) {
        int t = t0 + tid;
        int i = t >> 7, j = t & 127;
        smem[LDS_W1 + j * 64 + i] = w1[t];          // transpose on the fly
    }
#pragma unroll
    for (int t0 = 0; t0 < 2048; t0 += 256) {
        int t = t0 + tid;
        reinterpret_cast<float4*>(smem + LDS_W2)[t] =
            reinterpret_cast<const float4*>(w2)[t];
    }
    if (tid < 128) smem[LDS_B1 + tid] = b1[tid];
    if (tid < 64) {
        smem[LDS_B2 + tid] = b2[tid];
        smem[LDS_LG + tid] = ln_g[tid];
        smem[LDS_LB + tid] = ln_b[tid];
    }
    __syncthreads();

    const int token = blockIdx.x * 256 + tid;
    const int idx = seq[token];

    float h[64];
    const float4* er = reinterpret_cast<const float4*>(embed + idx * 64);
#pragma unroll
    for (int i = 0; i < 16; ++i) {
        float4 v = er[i];
        h[4 * i + 0] = v.x; h[4 * i + 1] = v.y;
        h[4 * i + 2] = v.z; h[4 * i + 3] = v.w;
    }

    float x[64];
#pragma unroll
    for (int m = 0; m < 64; ++m) x[m] = smem[LDS_B2 + m];

#pragma unroll 2
    for (int j = 0; j < 128; ++j) {
        const float4* w1r = reinterpret_cast<const float4*>(smem + LDS_W1 + j * 64);
        float a0 = 0.f, a1 = 0.f, a2 = 0.f, a3 = 0.f;
#pragma unroll
        for (int i = 0; i < 16; ++i) {
            float4 w = w1r[i];
            a0 = fmaf(h[4 * i + 0], w.x, a0);
            a1 = fmaf(h[4 * i + 1], w.y, a1);
            a2 = fmaf(h[4 * i + 2], w.z, a2);
            a3 = fmaf(h[4 * i + 3], w.w, a3);
        }
        float acc = fmaxf(smem[LDS_B1 + j] + ((a0 + a1) + (a2 + a3)), 0.f);
        const float4* w2r = reinterpret_cast<const float4*>(smem + LDS_W2 + j * 64);
#pragma unroll
        for (int m = 0; m < 16; ++m) {
            float4 w = w2r[m];
            x[4 * m + 0] = fmaf(acc, w.x, x[4 * m + 0]);
            x[4 * m + 1] = fmaf(acc, w.y, x[4 * m + 1]);
            x[4 * m + 2] = fmaf(acc, w.z, x[4 * m + 2]);
            x[4 * m + 3] = fmaf(acc, w.w, x[4 * m + 3]);
        }
    }

    // residual
#pragma unroll
    for (int m = 0; m < 64; ++m) x[m] += h[m];

    // LayerNorm (lane-local)
    float s0 = 0.f, s1 = 0.f;
#pragma unroll
    for (int m = 0; m < 64; m += 2) { s0 += x[m]; s1 += x[m + 1]; }
    float mu = (s0 + s1) * (1.f / 64.f);
    float v0 = 0.f, v1 = 0.f;
#pragma unroll
    for (int m = 0; m < 64; m += 2) {
        float d0 = x[m] - mu, d1 = x[m + 1] - mu;
        v0 = fmaf(d0, d0, v0);
        v1 = fmaf(d1, d1, v1);
    }
    float rstd = 1.f / sqrtf((v0 + v1) * (1.f / 64.f) + 1e-5f);

    float ss0 = 0.f, ss1 = 0.f;
#pragma unroll
    for (int m = 0; m < 64; ++m) {
        float k = fmaf((x[m] - mu) * rstd, smem[LDS_LG + m], smem[LDS_LB + m]);
        x[m] = k;
        if (m & 1) ss1 = fmaf(k, k, ss1); else ss0 = fmaf(k, k, ss0);
    }
    float s = fmaxf(sqrtf(ss0 + ss1), 1e-12f);
    float rn = 1.f / s;

    float4* kr = reinterpret_cast<float4*>(Kn + (size_t)token * 64);
#pragma unroll
    for (int i = 0; i < 16; ++i)
        kr[i] = make_float4(x[4 * i + 0] * rn, x[4 * i + 1] * rn,
                            x[4 * i + 2] * rn, x[4 * i + 3] * rn);
    S[token] = s;
}

// ---------------------------------------------------------------------------
// k2: delta-rule scan + head. One block (512 threads) per batch. Thread t owns
// M[r][c0..c0+7], r = t>>3, c0 = 8*(t&7). M in registers; kn rows prefetched.
// vp reduction = 3-stage DPP butterfly (pure VALU, no LDS pipe).
// Tail: y -> LDS -> (y@rp_w+rp_b)@out_w+out_b on 64 threads.
// ---------------------------------------------------------------------------
__global__ __launch_bounds__(512) void k2_scan(
    const float* __restrict__ Kn, const float* __restrict__ S,
    const float* __restrict__ rp_w, const float* __restrict__ rp_b,
    const float* __restrict__ out_w, const float* __restrict__ out_b,
    float* __restrict__ out)
{
    const int b = blockIdx.x;
    const int tid = threadIdx.x;
    const int r  = tid >> 3;     // row 0..63
    const int cg = tid & 7;      // column group 0..7

    const float* Kb  = Kn + (size_t)b * (SEQLEN * 64);
    const float* Kc  = Kb + cg * 8;
    const float* Kr  = Kb + r;
    const float* Sb  = S + b * SEQLEN;

    float M0 = 0.f, M1 = 0.f, M2 = 0.f, M3 = 0.f;
    float M4 = 0.f, M5 = 0.f, M6 = 0.f, M7 = 0.f;

    float4 ca = *reinterpret_cast<const float4*>(Kc);
    float4 cb = *reinterpret_cast<const float4*>(Kc + 4);
    float knr = *Kr;
    float s   = Sb[0];

    for (int l = 0; l < SEQLEN - 1; ++l) {
        // prefetch next kn row (row 511 = query on last iteration)
        const float* nx = Kc + (l + 1) * 64;
        float4 na = *reinterpret_cast<const float4*>(nx);
        float4 nb = *reinterpret_cast<const float4*>(nx + 4);
        float nknr = Kr[(l + 1) * 64];
        float ns   = Sb[l + 1];

        float p0 = fmaf(M0, ca.x, fmaf(M1, ca.y, fmaf(M2, ca.z, M3 * ca.w)));
        float p1 = fmaf(M4, cb.x, fmaf(M5, cb.y, fmaf(M6, cb.z, M7 * cb.w)));
        float vp = sum8(p0 + p1);

        float dv = fmaf(knr, s, -vp);   // raw k_r = kn_r * s

        M0 = fmaf(dv, ca.x, M0); M1 = fmaf(dv, ca.y, M1);
        M2 = fmaf(dv, ca.z, M2); M3 = fmaf(dv, ca.w, M3);
        M4 = fmaf(dv, cb.x, M4); M5 = fmaf(dv, cb.y, M5);
        M6 = fmaf(dv, cb.z, M6); M7 = fmaf(dv, cb.w, M7);

        ca = na; cb = nb; knr = nknr; s = ns;
    }

    // ca/cb = normalized row 511, s = its norm scale; query = kn*s
    float y = fmaf(M0, ca.x, fmaf(M1, ca.y, fmaf(M2, ca.z, fmaf(M3, ca.w,
              fmaf(M4, cb.x, fmaf(M5, cb.y, fmaf(M6, cb.z, M7 * cb.w)))))));
    y = sum8(y) * s;

    // ---- head: out = (y @ rp_w + rp_b) @ out_w + out_b ----
    __shared__ float sy[64];
    __shared__ float sz[64];
    if (cg == 0) sy[r] = y;
    __syncthreads();
    if (tid < 64) {
        float z = rp_b[tid];
#pragma unroll
        for (int j = 0; j < 64; ++j) z = fmaf(sy[j], rp_w[j * 64 + tid], z);
        sz[tid] = z;
    }
    __syncthreads();
    if (tid < 64) {
        float o = out_b[tid];
#pragma unroll
        for (int i = 0; i < 64; ++i) o = fmaf(sz[i], out_w[i * 64 + tid], o);
        out[b * 64 + tid] = o;
    }
}

// ---------------------------------------------------------------------------
extern "C" void kernel_launch(void* const* d_in, const int* in_sizes, int n_in,
                              void* d_out, int out_size, void* d_ws, size_t ws_size,
                              hipStream_t stream) {
    const int*   seq   = (const int*)d_in[0];
    const float* embed = (const float*)d_in[1];
    const float* w1    = (const float*)d_in[2];
    const float* b1    = (const float*)d_in[3];
    const float* w2    = (const float*)d_in[4];
    const float* b2    = (const float*)d_in[5];
    const float* ln_g  = (const float*)d_in[6];
    const float* ln_b  = (const float*)d_in[7];
    const float* rp_w  = (const float*)d_in[8];
    const float* rp_b  = (const float*)d_in[9];
    const float* out_w = (const float*)d_in[10];
    const float* out_b = (const float*)d_in[11];
    float* out = (float*)d_out;

    float* wsf = (float*)d_ws;
    float* Kn = wsf;                       // 256*512*64 = 8388608 floats
    float* S  = Kn + 8388608;              // 256*512    = 131072 floats

    k1_token<<<512, 256, 0, stream>>>(seq, embed, w1, b1, w2, b2,
                                      ln_g, ln_b, Kn, S);
    k2_scan<<<NBATCH, 512, 0, stream>>>(Kn, S, rp_w, rp_b, out_w, out_b, out);
}

// Round 3
// 410.387 us; speedup vs baseline: 1.2650x; 1.2650x over previous
//
#include <hip/hip_runtime.h>

#define HD 64
#define SEQLEN 512
#define NBATCH 256

// DPP controls
#define DPP_XOR1 0xB1     // quad_perm [1,0,3,2]
#define DPP_XOR2 0x4E     // quad_perm [2,3,0,1]
#define DPP_HMIR 0x141    // row_half_mirror (i <-> 7-i within 8 lanes)

__device__ __forceinline__ float dpp_add(float x, const int ctrl) {
    int y;
    switch (ctrl) {  // ctrl must be an immediate for the builtin
        case DPP_XOR1:
            y = __builtin_amdgcn_update_dpp(0, __float_as_int(x), DPP_XOR1, 0xf, 0xf, true);
            break;
        case DPP_XOR2:
            y = __builtin_amdgcn_update_dpp(0, __float_as_int(x), DPP_XOR2, 0xf, 0xf, true);
            break;
        default:
            y = __builtin_amdgcn_update_dpp(0, __float_as_int(x), DPP_HMIR, 0xf, 0xf, true);
            break;
    }
    return x + __int_as_float(y);
}

__device__ __forceinline__ float sum8(float x) {
    x = dpp_add(x, DPP_XOR1);
    x = dpp_add(x, DPP_XOR2);
    x = dpp_add(x, DPP_HMIR);
    return x;   // all 8 lanes of the group hold the sum
}

// ---------------------------------------------------------------------------
// k0: transpose w1 [64][128] -> w1t [128][64] (contiguous columns for s_load).
// ---------------------------------------------------------------------------
__global__ __launch_bounds__(256) void k0_transpose(const float* __restrict__ w1,
                                                    float* __restrict__ w1t) {
    int t = blockIdx.x * 256 + threadIdx.x;
    if (t < 64 * 128) {
        int i = t >> 7;      // row in w1   (0..63)
        int j = t & 127;     // col in w1   (0..127)
        w1t[j * 64 + i] = w1[t];
    }
}

// ---------------------------------------------------------------------------
// k1: 2-way j-split per token. Block = 256 threads = 128 tokens x 2 halves.
// Waves 0-1 (hf=0): j in [0,64); waves 2-3 (hf=1): j in [64,128).
// Weight rows are wave-uniform -> s_load broadcast. Partial x[64] combined
// via a swizzled LDS exchange; half 0 finishes residual + LN + normalize.
// Outputs: Kn[token][64] normalized keys, S[token] = max(||k||,1e-12).
// ---------------------------------------------------------------------------
__global__ __launch_bounds__(256) void k1_token(
    const int* __restrict__ seq, const float* __restrict__ embed,
    const float* __restrict__ w1t, const float* __restrict__ b1,
    const float* __restrict__ w2, const float* __restrict__ b2,
    const float* __restrict__ ln_g, const float* __restrict__ ln_b,
    float* __restrict__ Kn, float* __restrict__ S)
{
    __shared__ float4 sx[128 * 16];   // 32 KB partial-x exchange

    const int tid = threadIdx.x;
    const int tl  = tid & 127;        // token within block
    const int hf  = tid >> 7;         // j-half
    const int token = blockIdx.x * 128 + tl;

    const int idx = seq[token];
    float h[64];
    const float4* er = reinterpret_cast<const float4*>(embed + idx * 64);
#pragma unroll
    for (int i = 0; i < 16; ++i) {
        float4 v = er[i];
        h[4 * i + 0] = v.x; h[4 * i + 1] = v.y;
        h[4 * i + 2] = v.z; h[4 * i + 3] = v.w;
    }

    float x[64];
#pragma unroll
    for (int m = 0; m < 64; ++m) x[m] = 0.f;

    const int jbase = hf * 64;
#pragma unroll 2
    for (int j = 0; j < 64; ++j) {
        const int jj = jbase + j;
        const float* w1r = w1t + jj * 64;   // uniform -> s_load
        float a0 = 0.f, a1 = 0.f, a2 = 0.f, a3 = 0.f;
#pragma unroll
        for (int i = 0; i < 64; i += 4) {
            a0 = fmaf(h[i + 0], w1r[i + 0], a0);
            a1 = fmaf(h[i + 1], w1r[i + 1], a1);
            a2 = fmaf(h[i + 2], w1r[i + 2], a2);
            a3 = fmaf(h[i + 3], w1r[i + 3], a3);
        }
        float acc = fmaxf(b1[jj] + ((a0 + a1) + (a2 + a3)), 0.f);
        const float* w2r = w2 + jj * 64;    // uniform -> s_load
#pragma unroll
        for (int m = 0; m < 64; ++m) x[m] = fmaf(acc, w2r[m], x[m]);
    }

    if (hf == 1) {
#pragma unroll
        for (int e = 0; e < 16; ++e)
            sx[tl * 16 + ((e + tl) & 15)] =
                make_float4(x[4 * e + 0], x[4 * e + 1], x[4 * e + 2], x[4 * e + 3]);
    }
    __syncthreads();
    if (hf == 1) return;

    // half 0: combine + residual + bias
#pragma unroll
    for (int e = 0; e < 16; ++e) {
        float4 p = sx[tl * 16 + ((e + tl) & 15)];
        x[4 * e + 0] += p.x + h[4 * e + 0] + b2[4 * e + 0];
        x[4 * e + 1] += p.y + h[4 * e + 1] + b2[4 * e + 1];
        x[4 * e + 2] += p.z + h[4 * e + 2] + b2[4 * e + 2];
        x[4 * e + 3] += p.w + h[4 * e + 3] + b2[4 * e + 3];
    }

    // LayerNorm (lane-local, population variance)
    float s0 = 0.f, s1 = 0.f;
#pragma unroll
    for (int m = 0; m < 64; m += 2) { s0 += x[m]; s1 += x[m + 1]; }
    float mu = (s0 + s1) * (1.f / 64.f);
    float v0 = 0.f, v1 = 0.f;
#pragma unroll
    for (int m = 0; m < 64; m += 2) {
        float d0 = x[m] - mu, d1 = x[m + 1] - mu;
        v0 = fmaf(d0, d0, v0);
        v1 = fmaf(d1, d1, v1);
    }
    float rstd = 1.f / sqrtf((v0 + v1) * (1.f / 64.f) + 1e-5f);

    float ss0 = 0.f, ss1 = 0.f;
#pragma unroll
    for (int m = 0; m < 64; ++m) {
        float k = fmaf((x[m] - mu) * rstd, ln_g[m], ln_b[m]);
        x[m] = k;
        if (m & 1) ss1 = fmaf(k, k, ss1); else ss0 = fmaf(k, k, ss0);
    }
    float s = fmaxf(sqrtf(ss0 + ss1), 1e-12f);
    float rn = 1.f / s;

    float4* kr = reinterpret_cast<float4*>(Kn + (size_t)token * 64);
#pragma unroll
    for (int i = 0; i < 16; ++i)
        kr[i] = make_float4(x[4 * i + 0] * rn, x[4 * i + 1] * rn,
                            x[4 * i + 2] * rn, x[4 * i + 3] * rn);
    S[token] = s;
}

// ---------------------------------------------------------------------------
// k2: delta-rule scan + head. One block (512 threads) per batch. Thread t owns
// M[r][c0..c0+7]. Depth-8 double-banked register prefetch: one bank's 8 rows
// load while the other bank's 8 steps compute (~360cy chain hides L2/L3).
// All prefetch arrays are fully unrolled (static indices -> registers).
// ---------------------------------------------------------------------------
#define LOADCHUNK(Pa, Pb, Pk, Ps, baseRow) do {                               \
    _Pragma("unroll")                                                         \
    for (int q = 0; q < 8; ++q) {                                             \
        const float* rp_ = Kc + (size_t)((baseRow) + q) * 64;                 \
        Pa[q] = *reinterpret_cast<const float4*>(rp_);                        \
        Pb[q] = *reinterpret_cast<const float4*>(rp_ + 4);                    \
        Pk[q] = Kr[((baseRow) + q) * 64];                                     \
        Ps[q] = Sb[(baseRow) + q];                                            \
    } } while (0)

__global__ __launch_bounds__(512) void k2_scan(
    const float* __restrict__ Kn, const float* __restrict__ S,
    const float* __restrict__ rp_w, const float* __restrict__ rp_b,
    const float* __restrict__ out_w, const float* __restrict__ out_b,
    float* __restrict__ out)
{
    const int b = blockIdx.x;
    const int tid = threadIdx.x;
    const int r  = tid >> 3;     // row 0..63
    const int cg = tid & 7;      // column group 0..7

    const float* Kb = Kn + (size_t)b * (SEQLEN * 64);
    const float* Kc = Kb + cg * 8;
    const float* Kr = Kb + r;
    const float* Sb = S + b * SEQLEN;

    float M0 = 0.f, M1 = 0.f, M2 = 0.f, M3 = 0.f;
    float M4 = 0.f, M5 = 0.f, M6 = 0.f, M7 = 0.f;

    auto step = [&](float4 a, float4 bb, float knr, float s_) {
        float p0 = fmaf(M0, a.x, fmaf(M1, a.y, fmaf(M2, a.z, M3 * a.w)));
        float p1 = fmaf(M4, bb.x, fmaf(M5, bb.y, fmaf(M6, bb.z, M7 * bb.w)));
        float vp = sum8(p0 + p1);
        float dv = fmaf(knr, s_, -vp);   // raw k_r = kn_r * s
        M0 = fmaf(dv, a.x, M0); M1 = fmaf(dv, a.y, M1);
        M2 = fmaf(dv, a.z, M2); M3 = fmaf(dv, a.w, M3);
        M4 = fmaf(dv, bb.x, M4); M5 = fmaf(dv, bb.y, M5);
        M6 = fmaf(dv, bb.z, M6); M7 = fmaf(dv, bb.w, M7);
    };

    float4 Aa[8], Ab[8]; float Ak[8], As[8];
    float4 Ba[8], Bb[8]; float Bk[8], Bs[8];

    LOADCHUNK(Aa, Ab, Ak, As, 0);

    for (int c = 0; c < 62; c += 2) {
        LOADCHUNK(Ba, Bb, Bk, Bs, (c + 1) * 8);
#pragma unroll
        for (int q = 0; q < 8; ++q) step(Aa[q], Ab[q], Ak[q], As[q]);
        LOADCHUNK(Aa, Ab, Ak, As, (c + 2) * 8);
#pragma unroll
        for (int q = 0; q < 8; ++q) step(Ba[q], Bb[q], Bk[q], Bs[q]);
    }
    // bank A holds chunk 62 (rows 496..503); load final chunk 63 (rows 504..511)
    LOADCHUNK(Ba, Bb, Bk, Bs, 504);
#pragma unroll
    for (int q = 0; q < 8; ++q) step(Aa[q], Ab[q], Ak[q], As[q]);   // l=496..503
#pragma unroll
    for (int q = 0; q < 7; ++q) step(Ba[q], Bb[q], Bk[q], Bs[q]);   // l=504..510

    // query = row 511 (normalized last token; rescale by its norm Bs[7])
    float4 qa = Ba[7], qb = Bb[7];
    float y = fmaf(M0, qa.x, fmaf(M1, qa.y, fmaf(M2, qa.z, fmaf(M3, qa.w,
              fmaf(M4, qb.x, fmaf(M5, qb.y, fmaf(M6, qb.z, M7 * qb.w)))))));
    y = sum8(y) * Bs[7];

    // ---- head: out = (y @ rp_w + rp_b) @ out_w + out_b ----
    __shared__ float sy[64];
    __shared__ float sz[64];
    if (cg == 0) sy[r] = y;
    __syncthreads();
    if (tid < 64) {
        float z = rp_b[tid];
#pragma unroll
        for (int j = 0; j < 64; ++j) z = fmaf(sy[j], rp_w[j * 64 + tid], z);
        sz[tid] = z;
    }
    __syncthreads();
    if (tid < 64) {
        float o = out_b[tid];
#pragma unroll
        for (int i = 0; i < 64; ++i) o = fmaf(sz[i], out_w[i * 64 + tid], o);
        out[b * 64 + tid] = o;
    }
}

// ---------------------------------------------------------------------------
extern "C" void kernel_launch(void* const* d_in, const int* in_sizes, int n_in,
                              void* d_out, int out_size, void* d_ws, size_t ws_size,
                              hipStream_t stream) {
    const int*   seq   = (const int*)d_in[0];
    const float* embed = (const float*)d_in[1];
    const float* w1    = (const float*)d_in[2];
    const float* b1    = (const float*)d_in[3];
    const float* w2    = (const float*)d_in[4];
    const float* b2    = (const float*)d_in[5];
    const float* ln_g  = (const float*)d_in[6];
    const float* ln_b  = (const float*)d_in[7];
    const float* rp_w  = (const float*)d_in[8];
    const float* rp_b  = (const float*)d_in[9];
    const float* out_w = (const float*)d_in[10];
    const float* out_b = (const float*)d_in[11];
    float* out = (float*)d_out;

    float* wsf = (float*)d_ws;
    float* w1t = wsf;                      // 128*64     = 8192 floats
    float* Kn  = wsf + 8192;               // 256*512*64 = 8388608 floats
    float* S   = Kn + 8388608;             // 256*512    = 131072 floats

    k0_transpose<<<32, 256, 0, stream>>>(w1, w1t);
    k1_token<<<1024, 256, 0, stream>>>(seq, embed, w1t, b1, w2, b2,
                                       ln_g, ln_b, Kn, S);
    k2_scan<<<NBATCH, 512, 0, stream>>>(Kn, S, rp_w, rp_b, out_w, out_b, out);
}

// Round 5
// 169.778 us; speedup vs baseline: 3.0577x; 2.4172x over previous
//
#include <hip/hip_runtime.h>

#define SEQLEN 512
#define NBATCH 256

typedef __attribute__((ext_vector_type(8))) __bf16 bf16x8;
typedef __attribute__((ext_vector_type(4))) float f32x4;
typedef unsigned short u16;
typedef unsigned int u32;

union B8 { bf16x8 v; u16 s[8]; uint4 q; };

__device__ __forceinline__ u16 rneb(float f) {   // f32 -> bf16 bits, RNE
    u32 u = __float_as_uint(f);
    return (u16)((u + 0x7FFFu + ((u >> 16) & 1u)) >> 16);
}

template <int CTRL>
__device__ __forceinline__ float dpp_add(float x) {
    int y = __builtin_amdgcn_update_dpp(0, __float_as_int(x), CTRL, 0xF, 0xF, true);
    return x + __int_as_float(y);
}
// sum across each aligned 16-lane group (pure VALU/DPP, no LDS pipe)
__device__ __forceinline__ float sum16(float x) {
    x = dpp_add<0xB1>(x);     // quad_perm [1,0,3,2]  : xor 1
    x = dpp_add<0x4E>(x);     // quad_perm [2,3,0,1]  : xor 2
    x = dpp_add<0x141>(x);    // row_half_mirror      : cross quads within 8
    x = dpp_add<0x140>(x);    // row_mirror           : cross 8s within 16
    return x;
}

// ---------------------------------------------------------------------------
// k0: weight prep. w1t[j][i] = bf16(w1[i][j])  (128x64);
//                  w2t[m][j] = bf16(w2[j][m])  (64x128).
// ---------------------------------------------------------------------------
__global__ __launch_bounds__(256) void k0_prep(const float* __restrict__ w1,
                                               const float* __restrict__ w2,
                                               u16* __restrict__ w1t,
                                               u16* __restrict__ w2t) {
    int t = blockIdx.x * 256 + threadIdx.x;     // 0..16383
    if (t < 8192) {
        int j = t >> 6, i = t & 63;
        w1t[t] = rneb(w1[i * 128 + j]);
    } else {
        int t2 = t - 8192;
        int m = t2 >> 7, j = t2 & 127;
        w2t[t2] = rneb(w2[j * 64 + m]);
    }
}

// ---------------------------------------------------------------------------
// k1: MFMA front-end. Block = 256 thr = 4 waves; each wave owns 16 tokens.
// GEMM1: t1^T[128x16] = w1^T @ X^T via 8 ntiles x 2 ksteps of 16x16x32 bf16.
// t1 -> relu -> bf16 -> XOR-swizzled LDS -> re-fragment -> GEMM2:
// ff^T[64x16] = w2^T @ t1^T (4 mtiles x 4 ksteps). Epilogue: +h(f32)+b2,
// LayerNorm (lane-local + shfl16/32), normalize, store Kn + S.
// C/D layout (measured m89): col = lane&15 (token), row = 4*(lane>>4)+reg.
// ---------------------------------------------------------------------------
__global__ __launch_bounds__(256) void k1_mlp(
    const int* __restrict__ seq, const float* __restrict__ embed,
    const u16* __restrict__ w1t, const float* __restrict__ b1,
    const u16* __restrict__ w2t, const float* __restrict__ b2,
    const float* __restrict__ ln_g, const float* __restrict__ ln_b,
    float* __restrict__ Kn, float* __restrict__ S)
{
    __shared__ u16 t1s[4][2048];          // per-wave [16 tok][128 j] bf16, 16 KB
    const int tid = threadIdx.x;
    const int wv = tid >> 6;
    const int l  = tid & 63;
    const int g  = l >> 4;                 // k-chunk / row group
    const int tl = l & 15;                 // token-in-wave == B col == D col
    const int tok = blockIdx.x * 64 + wv * 16 + tl;

    const int idx = seq[tok];
    const float* erow = embed + idx * 64;

    // B-fragments for GEMM1: X[tok][kk*32 + 8g + e], e=0..7
    B8 xb0, xb1;
    {
        float4 c0 = *reinterpret_cast<const float4*>(erow + g * 8);
        float4 c1 = *reinterpret_cast<const float4*>(erow + g * 8 + 4);
        xb0.s[0] = rneb(c0.x); xb0.s[1] = rneb(c0.y); xb0.s[2] = rneb(c0.z); xb0.s[3] = rneb(c0.w);
        xb0.s[4] = rneb(c1.x); xb0.s[5] = rneb(c1.y); xb0.s[6] = rneb(c1.z); xb0.s[7] = rneb(c1.w);
        float4 c2 = *reinterpret_cast<const float4*>(erow + 32 + g * 8);
        float4 c3 = *reinterpret_cast<const float4*>(erow + 32 + g * 8 + 4);
        xb1.s[0] = rneb(c2.x); xb1.s[1] = rneb(c2.y); xb1.s[2] = rneb(c2.z); xb1.s[3] = rneb(c2.w);
        xb1.s[4] = rneb(c3.x); xb1.s[5] = rneb(c3.y); xb1.s[6] = rneb(c3.z); xb1.s[7] = rneb(c3.w);
    }

    // GEMM1: A = w1^T tile rows nt*16+tl, k = kk*32 + 8g + e (same k-map as B)
    f32x4 acc[8];
#pragma unroll
    for (int nt = 0; nt < 8; ++nt) acc[nt] = (f32x4){0.f, 0.f, 0.f, 0.f};
#pragma unroll
    for (int nt = 0; nt < 8; ++nt) {
        const u16* arow = w1t + (nt * 16 + tl) * 64 + g * 8;
        B8 a0; a0.q = *reinterpret_cast<const uint4*>(arow);
        acc[nt] = __builtin_amdgcn_mfma_f32_16x16x32_bf16(a0.v, xb0.v, acc[nt], 0, 0, 0);
        B8 a1; a1.q = *reinterpret_cast<const uint4*>(arow + 32);
        acc[nt] = __builtin_amdgcn_mfma_f32_16x16x32_bf16(a1.v, xb1.v, acc[nt], 0, 0, 0);
    }

    // bias + relu + bf16, write to swizzled LDS (j ^ ((tok&7)<<3))
    const int swz = (tl & 7) << 3;
    u16* myT = &t1s[wv][tl * 128];
#pragma unroll
    for (int nt = 0; nt < 8; ++nt) {
        float4 bb = *reinterpret_cast<const float4*>(b1 + nt * 16 + g * 4);
        u32 lo = (u32)rneb(fmaxf(acc[nt][0] + bb.x, 0.f)) |
                 ((u32)rneb(fmaxf(acc[nt][1] + bb.y, 0.f)) << 16);
        u32 hi = (u32)rneb(fmaxf(acc[nt][2] + bb.z, 0.f)) |
                 ((u32)rneb(fmaxf(acc[nt][3] + bb.w, 0.f)) << 16);
        *reinterpret_cast<uint2*>(&myT[(nt * 16 + g * 4) ^ swz]) = make_uint2(lo, hi);
    }

    // GEMM2: A = w2^T rows mt*16+tl, k-dim = j (128), B = t1^T from LDS
    f32x4 acc2[4];
#pragma unroll
    for (int mt = 0; mt < 4; ++mt) acc2[mt] = (f32x4){0.f, 0.f, 0.f, 0.f};
#pragma unroll
    for (int kk = 0; kk < 4; ++kk) {
        B8 tb; tb.q = *reinterpret_cast<const uint4*>(&myT[(kk * 32 + g * 8) ^ swz]);
#pragma unroll
        for (int mt = 0; mt < 4; ++mt) {
            B8 a; a.q = *reinterpret_cast<const uint4*>(w2t + (mt * 16 + tl) * 128 + kk * 32 + g * 8);
            acc2[mt] = __builtin_amdgcn_mfma_f32_16x16x32_bf16(a.v, tb.v, acc2[mt], 0, 0, 0);
        }
    }

    // epilogue: x = ff + h + b2 ; LN ; normalize ; store.  m = mt*16 + 4g + r
    float x[16];
    float sum = 0.f;
#pragma unroll
    for (int mt = 0; mt < 4; ++mt) {
        float4 hr  = *reinterpret_cast<const float4*>(erow + mt * 16 + g * 4);
        float4 b2v = *reinterpret_cast<const float4*>(b2 + mt * 16 + g * 4);
        x[4*mt+0] = acc2[mt][0] + hr.x + b2v.x;
        x[4*mt+1] = acc2[mt][1] + hr.y + b2v.y;
        x[4*mt+2] = acc2[mt][2] + hr.z + b2v.z;
        x[4*mt+3] = acc2[mt][3] + hr.w + b2v.w;
        sum += x[4*mt+0] + x[4*mt+1] + x[4*mt+2] + x[4*mt+3];
    }
    sum += __shfl_xor(sum, 16);
    sum += __shfl_xor(sum, 32);
    float mu = sum * (1.f / 64.f);

    float vs = 0.f;
#pragma unroll
    for (int i = 0; i < 16; ++i) { float d = x[i] - mu; vs = fmaf(d, d, vs); }
    vs += __shfl_xor(vs, 16);
    vs += __shfl_xor(vs, 32);
    float rstd = 1.f / sqrtf(vs * (1.f / 64.f) + 1e-5f);

    float ss = 0.f;
#pragma unroll
    for (int mt = 0; mt < 4; ++mt) {
        float4 gv = *reinterpret_cast<const float4*>(ln_g + mt * 16 + g * 4);
        float4 bv = *reinterpret_cast<const float4*>(ln_b + mt * 16 + g * 4);
        float k0 = fmaf((x[4*mt+0] - mu) * rstd, gv.x, bv.x);
        float k1 = fmaf((x[4*mt+1] - mu) * rstd, gv.y, bv.y);
        float k2 = fmaf((x[4*mt+2] - mu) * rstd, gv.z, bv.z);
        float k3 = fmaf((x[4*mt+3] - mu) * rstd, gv.w, bv.w);
        x[4*mt+0] = k0; x[4*mt+1] = k1; x[4*mt+2] = k2; x[4*mt+3] = k3;
        ss = fmaf(k0, k0, ss); ss = fmaf(k1, k1, ss);
        ss = fmaf(k2, k2, ss); ss = fmaf(k3, k3, ss);
    }
    ss += __shfl_xor(ss, 16);
    ss += __shfl_xor(ss, 32);
    float s = fmaxf(sqrtf(ss), 1e-12f);
    float rn = 1.f / s;

    float* krow = Kn + (size_t)tok * 64;
#pragma unroll
    for (int mt = 0; mt < 4; ++mt)
        *reinterpret_cast<float4*>(krow + mt * 16 + g * 4) =
            make_float4(x[4*mt+0] * rn, x[4*mt+1] * rn, x[4*mt+2] * rn, x[4*mt+3] * rn);
    if (l < 16) S[tok] = s;
}

// ---------------------------------------------------------------------------
// k2: backward vector scan + head.  y = sum_t k_t (kn_t . u_t),
// u_{510} = q = kn_511*s_511,  u_{t-1} = u_t - kn_t (kn_t . u_t).
// 16 lanes per batch (4 batches/wave, 1 wave/block, 64 blocks).
// Lane holds u/y elems c16*4..+3. Per-step reduce = sum16 (pure DPP).
// 3-bank x 8-row register prefetch (~24 steps of lead > L3 latency).
// ---------------------------------------------------------------------------
#define KLOAD(KA, SA, CH) do {                                                \
    _Pragma("unroll")                                                         \
    for (int q = 0; q < 8; ++q) {                                             \
        int trow = 510 - 8 * (CH) - q;                                        \
        int cr = trow < 0 ? 0 : trow;                                         \
        KA[q] = *reinterpret_cast<const float4*>(Kb + (size_t)cr * 64 + c16 * 4); \
        SA[q] = Sb[cr];                                                       \
    } } while (0)

__global__ __launch_bounds__(64) void k2_scan(
    const float* __restrict__ Kn, const float* __restrict__ S,
    const float* __restrict__ rp_w, const float* __restrict__ rp_b,
    const float* __restrict__ out_w, const float* __restrict__ out_b,
    float* __restrict__ out)
{
    const int l = threadIdx.x;
    const int gb = l >> 4, c16 = l & 15;
    const int bt = blockIdx.x * 4 + gb;
    const float* Kb = Kn + (size_t)bt * (SEQLEN * 64);
    const float* Sb = S + bt * SEQLEN;

    float4 qi = *reinterpret_cast<const float4*>(Kb + 511 * 64 + c16 * 4);
    float s511 = Sb[511];
    float u0 = qi.x * s511, u1 = qi.y * s511, u2 = qi.z * s511, u3 = qi.w * s511;
    float y0 = 0.f, y1 = 0.f, y2 = 0.f, y3 = 0.f;

    auto step = [&](float4 kf, float st) {
        float p = fmaf(kf.x, u0, kf.y * u1) + fmaf(kf.z, u2, kf.w * u3);
        float c_ = sum16(p);
        float cs = c_ * st;
        u0 = fmaf(-c_, kf.x, u0); u1 = fmaf(-c_, kf.y, u1);
        u2 = fmaf(-c_, kf.z, u2); u3 = fmaf(-c_, kf.w, u3);
        y0 = fmaf(cs, kf.x, y0); y1 = fmaf(cs, kf.y, y1);
        y2 = fmaf(cs, kf.z, y2); y3 = fmaf(cs, kf.w, y3);
    };

    float4 bA[8], bB[8], bC[8];
    float  sA[8], sB[8], sC[8];

    KLOAD(bA, sA, 0);
    KLOAD(bB, sB, 1);
    for (int c = 0; c < 63; c += 3) {
        KLOAD(bC, sC, c + 2);
#pragma unroll
        for (int q = 0; q < 8; ++q) step(bA[q], sA[q]);
        KLOAD(bA, sA, c + 3);
#pragma unroll
        for (int q = 0; q < 8; ++q) step(bB[q], sB[q]);
        KLOAD(bB, sB, c + 4);
#pragma unroll
        for (int q = 0; q < 8; ++q) step(bC[q], sC[q]);
    }
    // tail: bank A holds chunk 63 -> t = 6..0 (q=0..6)
#pragma unroll
    for (int q = 0; q < 7; ++q) step(bA[q], sA[q]);

    // ---- fused head ----
    __shared__ float ybs[4][64];
    __shared__ float zbs[4][64];
    *reinterpret_cast<float4*>(&ybs[gb][c16 * 4]) = make_float4(y0, y1, y2, y3);
    __syncthreads();

    float z0 = rp_b[l], z1 = z0, z2 = z0, z3 = z0;
#pragma unroll 8
    for (int j = 0; j < 64; ++j) {
        float w = rp_w[j * 64 + l];
        z0 = fmaf(ybs[0][j], w, z0); z1 = fmaf(ybs[1][j], w, z1);
        z2 = fmaf(ybs[2][j], w, z2); z3 = fmaf(ybs[3][j], w, z3);
    }
    zbs[0][l] = z0; zbs[1][l] = z1; zbs[2][l] = z2; zbs[3][l] = z3;
    __syncthreads();

    float o0 = out_b[l], o1 = o0, o2 = o0, o3 = o0;
#pragma unroll 8
    for (int j = 0; j < 64; ++j) {
        float w = out_w[j * 64 + l];
        o0 = fmaf(zbs[0][j], w, o0); o1 = fmaf(zbs[1][j], w, o1);
        o2 = fmaf(zbs[2][j], w, o2); o3 = fmaf(zbs[3][j], w, o3);
    }
    const int bbase = blockIdx.x * 4;
    out[(bbase + 0) * 64 + l] = o0;
    out[(bbase + 1) * 64 + l] = o1;
    out[(bbase + 2) * 64 + l] = o2;
    out[(bbase + 3) * 64 + l] = o3;
}

// ---------------------------------------------------------------------------
extern "C" void kernel_launch(void* const* d_in, const int* in_sizes, int n_in,
                              void* d_out, int out_size, void* d_ws, size_t ws_size,
                              hipStream_t stream) {
    const int*   seq   = (const int*)d_in[0];
    const float* embed = (const float*)d_in[1];
    const float* w1    = (const float*)d_in[2];
    const float* b1    = (const float*)d_in[3];
    const float* w2    = (const float*)d_in[4];
    const float* b2    = (const float*)d_in[5];
    const float* ln_g  = (const float*)d_in[6];
    const float* ln_b  = (const float*)d_in[7];
    const float* rp_w  = (const float*)d_in[8];
    const float* rp_b  = (const float*)d_in[9];
    const float* out_w = (const float*)d_in[10];
    const float* out_b = (const float*)d_in[11];
    float* out = (float*)d_out;

    float* wsf = (float*)d_ws;
    u16*  w1t = (u16*)d_ws;                // 8192 u16 = 16 KB
    u16*  w2t = w1t + 8192;                // 8192 u16 = 16 KB
    float* Kn = wsf + 8192;                // 32 KB offset; 256*512*64 floats
    float* S  = Kn + 8388608;              // 256*512 floats

    k0_prep<<<64, 256, 0, stream>>>(w1, w2, w1t, w2t);
    k1_mlp<<<2048, 256, 0, stream>>>(seq, embed, w1t, b1, w2t, b2,
                                     ln_g, ln_b, Kn, S);
    k2_scan<<<64, 64, 0, stream>>>(Kn, S, rp_w, rp_b, out_w, out_b, out);
}

// Round 6
// 128.090 us; speedup vs baseline: 4.0529x; 1.3255x over previous
//
#include <hip/hip_runtime.h>

#define SEQLEN 512
#define NBATCH 256

typedef __attribute__((ext_vector_type(8))) __bf16 bf16x8;
typedef __attribute__((ext_vector_type(4))) float f32x4;
typedef unsigned short u16;
typedef unsigned int u32;

union B8 { bf16x8 v; u16 s[8]; uint4 q; };

__device__ __forceinline__ u16 rneb(float f) {   // f32 -> bf16 bits, RNE
    u32 u = __float_as_uint(f);
    return (u16)((u + 0x7FFFu + ((u >> 16) & 1u)) >> 16);
}

template <int CTRL>
__device__ __forceinline__ float dpp_add(float x) {
    int y = __builtin_amdgcn_update_dpp(0, __float_as_int(x), CTRL, 0xF, 0xF, true);
    return x + __int_as_float(y);
}
// sum across each aligned 16-lane group (pure VALU/DPP, no LDS pipe)
__device__ __forceinline__ float sum16(float x) {
    x = dpp_add<0xB1>(x);     // quad_perm [1,0,3,2]  : xor 1
    x = dpp_add<0x4E>(x);     // quad_perm [2,3,0,1]  : xor 2
    x = dpp_add<0x141>(x);    // row_half_mirror      : cross quads within 8
    x = dpp_add<0x140>(x);    // row_mirror           : cross 8s within 16
    return x;
}

// ---------------------------------------------------------------------------
// Fully fused: one block per batch (256 blocks x 256 threads, 1 block/CU).
// Phase A (4 waves): MLP+LN for the batch's 512 tokens -> kn rows in LDS
//   (XOR-swizzled: float col ^ ((row&7)<<3) -- scan reads conflict-free).
//   bf16 weight fragments live in registers (converted once at start).
// Phase B (wave 0): 511-step backward delta scan out of LDS.
//   y = sum_t k_t (kn_t . u_t), u_{510}=q, u_{t-1} = u_t - kn_t (kn_t . u_t).
// Phase C: head (y @ rp_w + rp_b) @ out_w + out_b on 64 threads.
// ---------------------------------------------------------------------------
__global__ __launch_bounds__(256, 1) void fused_all(
    const int* __restrict__ seq, const float* __restrict__ embed,
    const float* __restrict__ w1, const float* __restrict__ b1,
    const float* __restrict__ w2, const float* __restrict__ b2,
    const float* __restrict__ ln_g, const float* __restrict__ ln_b,
    const float* __restrict__ rp_w, const float* __restrict__ rp_b,
    const float* __restrict__ out_w, const float* __restrict__ out_b,
    float* __restrict__ out)
{
    __shared__ __align__(16) unsigned char smem[149504];
    float* Ksh = (float*)smem;                   // 512*64 f32 = 131072 B
    float* Ssh = (float*)(smem + 131072);        // 512 f32   = 2048 B
    u16*  t1b  = (u16*)(smem + 133120);          // 4 waves * 4096 B staging
    float* ysh = (float*)(smem + 133120);        // reuses t1 region (dead then)
    float* zsh = ysh + 64;

    const int tid = threadIdx.x;
    const int wv  = tid >> 6;
    const int l   = tid & 63;
    const int g   = l >> 4;                // k-chunk / row group
    const int tl  = l & 15;                // token-in-group == B col == D col
    const int b   = blockIdx.x;

    // ---- weight fragments -> registers (bf16), converted once ----
    // GEMM1 A: w1^T rows nt*16+tl; elem e is k = g*8+e (wA0) / 32+g*8+e (wA1)
    B8 wA0[8], wA1[8];
#pragma unroll
    for (int nt = 0; nt < 8; ++nt) {
        const int j = nt * 16 + tl;
#pragma unroll
        for (int e = 0; e < 8; ++e) {
            wA0[nt].s[e] = rneb(w1[(g * 8 + e) * 128 + j]);
            wA1[nt].s[e] = rneb(w1[(32 + g * 8 + e) * 128 + j]);
        }
    }
    // GEMM2 A: w2^T rows mt*16+tl; elem e is k = kk*32+g*8+e
    B8 wB[4][4];
#pragma unroll
    for (int kk = 0; kk < 4; ++kk)
#pragma unroll
        for (int mt = 0; mt < 4; ++mt) {
            const int m = mt * 16 + tl;
#pragma unroll
            for (int e = 0; e < 8; ++e)
                wB[kk][mt].s[e] = rneb(w2[(kk * 32 + g * 8 + e) * 64 + m]);
        }

    u16* myT = t1b + wv * 2048 + tl * 128;
    const int swz = (tl & 7) << 3;

    // ---- Phase A: MLP + LN, 8 groups of 16 tokens per wave ----
    for (int grp = 0; grp < 8; ++grp) {
        const int lt = wv * 128 + grp * 16 + tl;       // local token 0..511
        const int idx = seq[b * SEQLEN + lt];
        const float* erow = embed + idx * 64;

        // B-fragments: X[tok][k], k = g*8+e / 32+g*8+e
        B8 xb0, xb1;
        {
            float4 c0 = *reinterpret_cast<const float4*>(erow + g * 8);
            float4 c1 = *reinterpret_cast<const float4*>(erow + g * 8 + 4);
            xb0.s[0] = rneb(c0.x); xb0.s[1] = rneb(c0.y); xb0.s[2] = rneb(c0.z); xb0.s[3] = rneb(c0.w);
            xb0.s[4] = rneb(c1.x); xb0.s[5] = rneb(c1.y); xb0.s[6] = rneb(c1.z); xb0.s[7] = rneb(c1.w);
            float4 c2 = *reinterpret_cast<const float4*>(erow + 32 + g * 8);
            float4 c3 = *reinterpret_cast<const float4*>(erow + 32 + g * 8 + 4);
            xb1.s[0] = rneb(c2.x); xb1.s[1] = rneb(c2.y); xb1.s[2] = rneb(c2.z); xb1.s[3] = rneb(c2.w);
            xb1.s[4] = rneb(c3.x); xb1.s[5] = rneb(c3.y); xb1.s[6] = rneb(c3.z); xb1.s[7] = rneb(c3.w);
        }

        f32x4 acc[8];
#pragma unroll
        for (int nt = 0; nt < 8; ++nt) acc[nt] = (f32x4){0.f, 0.f, 0.f, 0.f};
#pragma unroll
        for (int nt = 0; nt < 8; ++nt) {
            acc[nt] = __builtin_amdgcn_mfma_f32_16x16x32_bf16(wA0[nt].v, xb0.v, acc[nt], 0, 0, 0);
            acc[nt] = __builtin_amdgcn_mfma_f32_16x16x32_bf16(wA1[nt].v, xb1.v, acc[nt], 0, 0, 0);
        }

        // bias + relu + bf16 -> per-wave swizzled LDS stage
#pragma unroll
        for (int nt = 0; nt < 8; ++nt) {
            float4 bb = *reinterpret_cast<const float4*>(b1 + nt * 16 + g * 4);
            u32 lo = (u32)rneb(fmaxf(acc[nt][0] + bb.x, 0.f)) |
                     ((u32)rneb(fmaxf(acc[nt][1] + bb.y, 0.f)) << 16);
            u32 hi = (u32)rneb(fmaxf(acc[nt][2] + bb.z, 0.f)) |
                     ((u32)rneb(fmaxf(acc[nt][3] + bb.w, 0.f)) << 16);
            *reinterpret_cast<uint2*>(&myT[(nt * 16 + g * 4) ^ swz]) = make_uint2(lo, hi);
        }

        // GEMM2
        f32x4 acc2[4];
#pragma unroll
        for (int mt = 0; mt < 4; ++mt) acc2[mt] = (f32x4){0.f, 0.f, 0.f, 0.f};
#pragma unroll
        for (int kk = 0; kk < 4; ++kk) {
            B8 tb; tb.q = *reinterpret_cast<const uint4*>(&myT[(kk * 32 + g * 8) ^ swz]);
#pragma unroll
            for (int mt = 0; mt < 4; ++mt)
                acc2[mt] = __builtin_amdgcn_mfma_f32_16x16x32_bf16(wB[kk][mt].v, tb.v, acc2[mt], 0, 0, 0);
        }

        // epilogue: x = ff + h + b2 ; LN ; normalize ; -> Ksh/Ssh
        float x[16];
        float sum = 0.f;
#pragma unroll
        for (int mt = 0; mt < 4; ++mt) {
            float4 hr  = *reinterpret_cast<const float4*>(erow + mt * 16 + g * 4);
            float4 b2v = *reinterpret_cast<const float4*>(b2 + mt * 16 + g * 4);
            x[4*mt+0] = acc2[mt][0] + hr.x + b2v.x;
            x[4*mt+1] = acc2[mt][1] + hr.y + b2v.y;
            x[4*mt+2] = acc2[mt][2] + hr.z + b2v.z;
            x[4*mt+3] = acc2[mt][3] + hr.w + b2v.w;
            sum += x[4*mt+0] + x[4*mt+1] + x[4*mt+2] + x[4*mt+3];
        }
        sum += __shfl_xor(sum, 16);
        sum += __shfl_xor(sum, 32);
        float mu = sum * (1.f / 64.f);

        float vs = 0.f;
#pragma unroll
        for (int i = 0; i < 16; ++i) { float d = x[i] - mu; vs = fmaf(d, d, vs); }
        vs += __shfl_xor(vs, 16);
        vs += __shfl_xor(vs, 32);
        float rstd = 1.f / sqrtf(vs * (1.f / 64.f) + 1e-5f);

        float ss = 0.f;
#pragma unroll
        for (int mt = 0; mt < 4; ++mt) {
            float4 gv = *reinterpret_cast<const float4*>(ln_g + mt * 16 + g * 4);
            float4 bv = *reinterpret_cast<const float4*>(ln_b + mt * 16 + g * 4);
            float k0 = fmaf((x[4*mt+0] - mu) * rstd, gv.x, bv.x);
            float k1 = fmaf((x[4*mt+1] - mu) * rstd, gv.y, bv.y);
            float k2 = fmaf((x[4*mt+2] - mu) * rstd, gv.z, bv.z);
            float k3 = fmaf((x[4*mt+3] - mu) * rstd, gv.w, bv.w);
            x[4*mt+0] = k0; x[4*mt+1] = k1; x[4*mt+2] = k2; x[4*mt+3] = k3;
            ss = fmaf(k0, k0, ss); ss = fmaf(k1, k1, ss);
            ss = fmaf(k2, k2, ss); ss = fmaf(k3, k3, ss);
        }
        ss += __shfl_xor(ss, 16);
        ss += __shfl_xor(ss, 32);
        float s = fmaxf(sqrtf(ss), 1e-12f);
        float rn = 1.f / s;

        // swizzled row write: float col ^ ((row&7)<<3); 16B alignment preserved
        const int rsw = (lt & 7) << 3;
#pragma unroll
        for (int mt = 0; mt < 4; ++mt)
            *reinterpret_cast<float4*>(Ksh + lt * 64 + ((mt * 16 + g * 4) ^ rsw)) =
                make_float4(x[4*mt+0] * rn, x[4*mt+1] * rn, x[4*mt+2] * rn, x[4*mt+3] * rn);
        if (l < 16) Ssh[lt] = s;
    }

    __syncthreads();

    // ---- Phase B: backward scan (wave 0; 4 redundant 16-lane groups) ----
    if (wv == 0) {
        const int c16 = l & 15;

        float4 qi = *reinterpret_cast<const float4*>(Ksh + 511 * 64 + ((c16 * 4) ^ 56));
        float s511 = Ssh[511];
        float u0 = qi.x * s511, u1 = qi.y * s511, u2 = qi.z * s511, u3 = qi.w * s511;
        float y0 = 0.f, y1 = 0.f, y2 = 0.f, y3 = 0.f;

        auto step = [&](float4 kf, float st) {
            float p = fmaf(kf.x, u0, kf.y * u1) + fmaf(kf.z, u2, kf.w * u3);
            float c_ = sum16(p);
            float cs = c_ * st;
            u0 = fmaf(-c_, kf.x, u0); u1 = fmaf(-c_, kf.y, u1);
            u2 = fmaf(-c_, kf.z, u2); u3 = fmaf(-c_, kf.w, u3);
            y0 = fmaf(cs, kf.x, y0); y1 = fmaf(cs, kf.y, y1);
            y2 = fmaf(cs, kf.z, y2); y3 = fmaf(cs, kf.w, y3);
        };

#define KLOADL(KA, SA, CH) do {                                               \
    _Pragma("unroll")                                                         \
    for (int q = 0; q < 8; ++q) {                                             \
        int trow = 510 - 8 * (CH) - q;                                        \
        int cr = trow < 0 ? 0 : trow;                                         \
        KA[q] = *reinterpret_cast<const float4*>(                             \
            Ksh + cr * 64 + ((c16 * 4) ^ ((cr & 7) << 3)));                   \
        SA[q] = Ssh[cr];                                                      \
    } } while (0)

        float4 bA[8], bB[8];
        float  sA[8], sB[8];
        KLOADL(bA, sA, 0);
        KLOADL(bB, sB, 1);
        for (int c = 0; c < 62; c += 2) {
#pragma unroll
            for (int q = 0; q < 8; ++q) step(bA[q], sA[q]);
            KLOADL(bA, sA, c + 2);
#pragma unroll
            for (int q = 0; q < 8; ++q) step(bB[q], sB[q]);
            KLOADL(bB, sB, c + 3);
        }
#pragma unroll
        for (int q = 0; q < 8; ++q) step(bA[q], sA[q]);   // chunk 62: t=14..7
#pragma unroll
        for (int q = 0; q < 7; ++q) step(bB[q], sB[q]);   // chunk 63: t=6..0

        if (l < 16)
            *reinterpret_cast<float4*>(&ysh[c16 * 4]) = make_float4(y0, y1, y2, y3);
    }
    __syncthreads();

    // ---- Phase C: head ----
    float z = 0.f;
    if (tid < 64) {
        z = rp_b[tid];
#pragma unroll 8
        for (int j = 0; j < 64; ++j) z = fmaf(ysh[j], rp_w[j * 64 + tid], z);
    }
    __syncthreads();        // ysh region re-read done before zsh write (alias-safe)
    if (tid < 64) zsh[tid] = z;
    __syncthreads();
    if (tid < 64) {
        float o = out_b[tid];
#pragma unroll 8
        for (int j = 0; j < 64; ++j) o = fmaf(zsh[j], out_w[j * 64 + tid], o);
        out[b * 64 + tid] = o;
    }
}

// ---------------------------------------------------------------------------
extern "C" void kernel_launch(void* const* d_in, const int* in_sizes, int n_in,
                              void* d_out, int out_size, void* d_ws, size_t ws_size,
                              hipStream_t stream) {
    const int*   seq   = (const int*)d_in[0];
    const float* embed = (const float*)d_in[1];
    const float* w1    = (const float*)d_in[2];
    const float* b1    = (const float*)d_in[3];
    const float* w2    = (const float*)d_in[4];
    const float* b2    = (const float*)d_in[5];
    const float* ln_g  = (const float*)d_in[6];
    const float* ln_b  = (const float*)d_in[7];
    const float* rp_w  = (const float*)d_in[8];
    const float* rp_b  = (const float*)d_in[9];
    const float* out_w = (const float*)d_in[10];
    const float* out_b = (const float*)d_in[11];
    float* out = (float*)d_out;

    fused_all<<<NBATCH, 256, 0, stream>>>(seq, embed, w1, b1, w2, b2,
                                          ln_g, ln_b, rp_w, rp_b,
                                          out_w, out_b, out);
}